// Round 14
// baseline (149.195 us; speedup 1.0000x reference)
//
#include <hip/hip_runtime.h>
#include <hip/hip_bf16.h>
#include <stdint.h>

#define AS1 __attribute__((address_space(1)))
#define AS3 __attribute__((address_space(3)))

typedef __bf16 bf16x8 __attribute__((ext_vector_type(8)));
typedef float  f32x4  __attribute__((ext_vector_type(4)));
typedef unsigned short ushort8v __attribute__((ext_vector_type(8)));
typedef unsigned short ushort4v __attribute__((ext_vector_type(4)));
typedef short short8v __attribute__((ext_vector_type(8)));
typedef short short4v __attribute__((ext_vector_type(4)));

__device__ __forceinline__ unsigned short f2bf(float f) {
    unsigned int u = __float_as_uint(f);
    u += 0x7fffu + ((u >> 16) & 1u);           // round-to-nearest-even
    return (unsigned short)(u >> 16);
}
__device__ __forceinline__ unsigned int pk2bf(float a, float b) {
    __hip_bfloat162 h = __float22bfloat162_rn(make_float2(a, b));  // x->low short
    unsigned int u;
    __builtin_memcpy(&u, &h, 4);
    return u;
}
__device__ __forceinline__ void g2lds16(const void* gp, void* lp) {
    __builtin_amdgcn_global_load_lds((AS1 void*)gp, (AS3 void*)lp, 16, 0, 0);
}
#define E2(x) __builtin_amdgcn_exp2f(x)

// ---------------- cast fp32 -> bf16 (x, Wq, Wk, Wv in one launch) -----------
__global__ __launch_bounds__(256) void cast_all(const float* __restrict__ x,
                                                const float* __restrict__ w0,
                                                const float* __restrict__ w1,
                                                const float* __restrict__ w2,
                                                unsigned short* __restrict__ xb,
                                                unsigned short* __restrict__ wc) {
    int id = blockIdx.x;
    const float* s;
    unsigned short* d;
    int base;
    if (id < 4096) { s = x; d = xb; base = id; }
    else {
        int z = (id - 4096) >> 10;
        s = (z == 0) ? w0 : (z == 1) ? w1 : w2;
        d = wc + (size_t)z * 1048576;
        base = (id - 4096) & 1023;
    }
    int i = (base * 256 + threadIdx.x) * 4;
    float4 v = *(const float4*)(s + i);
    ushort4v o = { f2bf(v.x), f2bf(v.y), f2bf(v.z), f2bf(v.w) };
    *(ushort4v*)(d + i) = o;
}

// ---------------- QKV GEMM: X @ W^T (NT), m97 structure (R9-exact) -----------
// Q (z=0) pre-scaled by 0.125*log2(e) so attn can exp2 scores directly.
__global__ __launch_bounds__(256) void gemm_qkv(const unsigned short* __restrict__ X,
                                                const unsigned short* __restrict__ W,
                                                unsigned short* __restrict__ QKV) {
    const int K = 1024, N = 1024;
    const int z = blockIdx.z;
    const unsigned short* A = X;
    const unsigned short* B = W + (size_t)z * (1024 * 1024);
    unsigned short* C = QKV + (size_t)z * (4096 * 1024);
    const float qs = (z == 0) ? 0.18033688011112042f : 1.0f;

    const int m0 = blockIdx.y * 128;
    const int n0 = blockIdx.x * 128;

    __shared__ unsigned short As[128 * 32];
    __shared__ unsigned short Bs[128 * 32];

    const int t = threadIdx.x;
    const int w = t >> 6;
    const int l = t & 63;
    const int wm = (w >> 1) * 64;
    const int wn = (w & 1) * 64;
    const int cl = l & 15;
    const int quad = l >> 4;

    const int srow = w * 16 + (l >> 2);
    const int scol = (l & 3) * 8;

    f32x4 acc[4][4] = {};

    for (int k0 = 0; k0 < K; k0 += 32) {
        g2lds16(A + (size_t)(m0 + srow) * K + k0 + scol,      As + w * 512);
        g2lds16(A + (size_t)(m0 + 64 + srow) * K + k0 + scol, As + 2048 + w * 512);
        g2lds16(B + (size_t)(n0 + srow) * K + k0 + scol,      Bs + w * 512);
        g2lds16(B + (size_t)(n0 + 64 + srow) * K + k0 + scol, Bs + 2048 + w * 512);
        __syncthreads();

        bf16x8 af[4], bfr[4];
        #pragma unroll
        for (int i = 0; i < 4; ++i)
            af[i] = *(const bf16x8*)(As + (wm + i * 16 + cl) * 32 + quad * 8);
        #pragma unroll
        for (int j = 0; j < 4; ++j)
            bfr[j] = *(const bf16x8*)(Bs + (wn + j * 16 + cl) * 32 + quad * 8);
        #pragma unroll
        for (int i = 0; i < 4; ++i)
            #pragma unroll
            for (int j = 0; j < 4; ++j)
                acc[i][j] = __builtin_amdgcn_mfma_f32_16x16x32_bf16(af[i], bfr[j], acc[i][j], 0, 0, 0);
        __syncthreads();
    }

    #pragma unroll
    for (int i = 0; i < 4; ++i) {
        #pragma unroll
        for (int r = 0; r < 4; ++r) {
            size_t row = (size_t)(m0 + wm + i * 16 + quad * 4 + r);
            #pragma unroll
            for (int j = 0; j < 4; ++j)
                C[row * N + (n0 + wn + j * 16 + cl)] = f2bf(acc[i][j][r] * qs);
        }
    }
}

// ---------------- V swizzle to VT3 (per bh) ---------------------------------
// VT3 element (tau, d) at (tau>>4)*1024 + (d&15)*64 + ((tau>>2)&3)*16
//                        + (d>>4)*4 + (tau&3)
__global__ __launch_bounds__(256) void vtrans(const unsigned short* __restrict__ Vn,
                                              unsigned short* __restrict__ V3) {
    const int bh = blockIdx.y;
    const int T0 = blockIdx.x * 128;
    __shared__ unsigned short L[128 * 72];
    const int t = threadIdx.x;

    const unsigned short* src = Vn + (size_t)bh * 131072 + (size_t)T0 * 64;
    #pragma unroll
    for (int p = 0; p < 4; ++p) {
        int r = p * 32 + (t >> 3), c = (t & 7) * 8;
        *(ushort8v*)(L + r * 72 + c) = *(const ushort8v*)(src + (size_t)r * 64 + c);
    }
    __syncthreads();
    unsigned short* dst = V3 + (size_t)bh * 131072 + (size_t)(T0 >> 4) * 1024;
    #pragma unroll
    for (int p = 0; p < 2; ++p) {
        int item = p * 256 + t;                 // 512 items: kb(8) x cl(16) x qk(4)
        int kb = item >> 6, cl = (item >> 2) & 15, qk = item & 3;
        ushort8v a, b;
        #pragma unroll
        for (int u = 0; u < 8; ++u) {
            int dt = u >> 2, j = u & 3;
            a[u] = L[(kb * 16 + qk * 4 + j) * 72 + dt * 16 + cl];
            b[u] = L[(kb * 16 + qk * 4 + j) * 72 + (dt + 2) * 16 + cl];
        }
        unsigned short* dp = dst + kb * 1024 + cl * 64 + qk * 16;
        *(ushort8v*)(dp) = a;
        *(ushort8v*)(dp + 8) = b;
    }
}

// ---------------- Flash attention: 128-kv chunks, two-half compute -----------
// R13 structure with DOUBLED chunk granularity: each barrier-step stages 32KB
// (K+V for 128 kv) and computes two sequential 64-kv halves (each half = the
// exact R13 body, so register peak is unchanged — R6 spill lesson). Barriers
// per block drop 34 -> 17; the async prefetch gets a 2x compute window.
// Diag chunk c==bb: half0 diagonal for waves 0-3 (full for 4-7); half1
// skipped by waves 0-3, diagonal for 4-7; mrel=(w&3)*16+cl (== w*16+cl-64h
// with h=w>>2 on diag paths). Bands paired (pp, 15-pp): 17 staged chunks per
// block, uniform over 256 blocks (1/CU; LDS 64KB dbuf is free at this grid).
// XCD-pinned (4 bh/XCD).
__global__ __launch_bounds__(512) void attn(const unsigned short* __restrict__ QK,
                                            const unsigned short* __restrict__ V3,
                                            float* __restrict__ Out) {
    const int id = blockIdx.x;                         // 256 blocks
    const int bh = (id & 7) * 4 + ((id >> 3) & 3);     // 4 bh per XCD
    const int pp = id >> 5;                            // band-pair 0..7
    const int t = threadIdx.x;                         // 0..511
    const int w = t >> 6;                              // wave 0..7
    const int l = t & 63;
    const int cl = l & 15;
    const int quad = l >> 4;
    const int c7 = cl & 7;

    const size_t bhoff = (size_t)bh * 131072;
    const unsigned short* Qb = QK + bhoff;
    const unsigned short* Kb = QK + (size_t)4194304 + bhoff;
    const unsigned short* Vb = V3 + bhoff;
    float* Ob = Out + bhoff;

    __shared__ unsigned short KVs[2][16384];           // per buf: K 8192 | V 8192

    // staging offsets: thread stages K granules {t, 512+t} and V {t, 512+t}
    // (R9-verified swizzle; formulas extend to 1024 granules / 128 rows)
    const int sgA = t, sgB = 512 + t;
    const int kOA = (sgA >> 3) * 64 + (((sgA & 7) ^ ((sgA >> 3) & 7)) * 8);
    const int kOB = (sgB >> 3) * 64 + (((sgB & 7) ^ ((sgB >> 3) & 7)) * 8);
    const int wgA = sgA & 63, wgB = sgB & 63;
    const int vOA = (sgA >> 6) * 512 + ((wgA ^ ((wgA >> 3) & 7)) * 8);
    const int vOB = (sgB >> 6) * 512 + ((wgB ^ ((wgB >> 3) & 7)) * 8);
    const int lB = w * 512;                            // shorts (wave-uniform)

    // read offsets (R9-verified); kt extends 0..7 via kt*1024
    const int oK0 = cl * 64 + (((quad)     ^ c7) * 8);
    const int oK1 = cl * 64 + (((quad + 4) ^ c7) * 8);
    const int oV0 = cl * 64 + (((quad * 2)     ^ c7) * 8);
    const int oV1 = cl * 64 + (((quad * 2 + 1) ^ c7) * 8);

    const int mrel = (w & 3) * 16 + cl;                // diag row rel. half base
    const bool wlow = (w < 4);

    #pragma unroll 1                                   // R6 lesson: no state merge
    for (int hb = 0; hb < 2; ++hb) {
        const int bb = hb ? (15 - pp) : pp;            // 128-row band index
        const int nch = bb + 1;                        // 128-kv chunks
        const int m0w = bb * 128 + w * 16;

        bf16x8 qf0, qf1;
        {
            const unsigned short* qa = Qb + (size_t)(m0w + cl) * 64 + quad * 8;
            qf0 = *(const bf16x8*)(qa);
            qf1 = *(const bf16x8*)(qa + 32);
        }

        f32x4 o[4] = {};
        float lps = 0.f;

        // stage chunk 0 into buf 0
        {
            unsigned short* s = &KVs[0][0];
            g2lds16(Kb + kOA, s + lB);
            g2lds16(Kb + kOB, s + 4096 + lB);
            g2lds16(Vb + vOA, s + 8192 + lB);
            g2lds16(Vb + vOB, s + 12288 + lB);
        }

        for (int c = 0; c < nch; ++c) {
            __syncthreads();                           // buf[c&1] ready
            if (c + 1 < nch) {
                const unsigned short* kg = Kb + (size_t)(c + 1) * 8192;
                const unsigned short* vg = Vb + (size_t)(c + 1) * 8192;
                unsigned short* s = &KVs[(c + 1) & 1][0];
                g2lds16(kg + kOA, s + lB);
                g2lds16(kg + kOB, s + 4096 + lB);
                g2lds16(vg + vOA, s + 8192 + lB);
                g2lds16(vg + vOB, s + 12288 + lB);
            }
            const unsigned short* Kl = &KVs[c & 1][0];
            const unsigned short* Vl = Kl + 8192;
            const bool diag = (c == nch - 1);

            #pragma unroll 1
            for (int h = 0; h < 2; ++h) {
                if (h == 1 && diag && wlow) break;     // fully-masked half (wave-uniform)
                const bool masked = diag && (wlow ? (h == 0) : (h == 1));
                const int kb0 = h * 4;                 // kt unit base for this half

                bf16x8 kf0[4], kf1[4];
                #pragma unroll
                for (int kt = 0; kt < 4; ++kt) {
                    kf0[kt] = *(const bf16x8*)(Kl + (kb0 + kt) * 1024 + oK0);
                    kf1[kt] = *(const bf16x8*)(Kl + (kb0 + kt) * 1024 + oK1);
                }
                f32x4 st[4] = {};
                #pragma unroll
                for (int kt = 0; kt < 4; ++kt) {
                    st[kt] = __builtin_amdgcn_mfma_f32_16x16x32_bf16(kf0[kt], qf0, st[kt], 0, 0, 0);
                    st[kt] = __builtin_amdgcn_mfma_f32_16x16x32_bf16(kf1[kt], qf1, st[kt], 0, 0, 0);
                }

                short4v pb[4];
                #pragma unroll
                for (int kt = 0; kt < 4; ++kt) {
                    float p0, p1, p2, p3;
                    if (masked) {
                        const int lk = kt * 16 + quad * 4;
                        p0 = (lk     <= mrel) ? E2(st[kt][0]) : 0.f;
                        p1 = (lk + 1 <= mrel) ? E2(st[kt][1]) : 0.f;
                        p2 = (lk + 2 <= mrel) ? E2(st[kt][2]) : 0.f;
                        p3 = (lk + 3 <= mrel) ? E2(st[kt][3]) : 0.f;
                    } else {
                        p0 = E2(st[kt][0]);
                        p1 = E2(st[kt][1]);
                        p2 = E2(st[kt][2]);
                        p3 = E2(st[kt][3]);
                    }
                    lps += (p0 + p1) + (p2 + p3);
                    uint2 u = { pk2bf(p0, p1), pk2bf(p2, p3) };
                    short4v pv;
                    __builtin_memcpy(&pv, &u, 8);
                    pb[kt] = pv;
                }

                #pragma unroll
                for (int kt = 0; kt < 4; ++kt) {
                    short8v v0 = *(const short8v*)(Vl + (kb0 + kt) * 1024 + oV0);  // dt 0,1
                    short8v v1 = *(const short8v*)(Vl + (kb0 + kt) * 1024 + oV1);  // dt 2,3
                    short4v a0 = __builtin_shufflevector(v0, v0, 0, 1, 2, 3);
                    short4v a1 = __builtin_shufflevector(v0, v0, 4, 5, 6, 7);
                    short4v a2 = __builtin_shufflevector(v1, v1, 0, 1, 2, 3);
                    short4v a3 = __builtin_shufflevector(v1, v1, 4, 5, 6, 7);
                    o[0] = __builtin_amdgcn_mfma_f32_16x16x16bf16_1k(a0, pb[kt], o[0], 0, 0, 0);
                    o[1] = __builtin_amdgcn_mfma_f32_16x16x16bf16_1k(a1, pb[kt], o[1], 0, 0, 0);
                    o[2] = __builtin_amdgcn_mfma_f32_16x16x16bf16_1k(a2, pb[kt], o[2], 0, 0, 0);
                    o[3] = __builtin_amdgcn_mfma_f32_16x16x16bf16_1k(a3, pb[kt], o[3], 0, 0, 0);
                }
            }
        }
        __syncthreads();                               // buf reuse across bands

        lps += __shfl_xor(lps, 16);
        lps += __shfl_xor(lps, 32);
        const float inv = 1.0f / lps;
        #pragma unroll
        for (int dt = 0; dt < 4; ++dt) {
            f32x4 r = o[dt];
            r[0] *= inv; r[1] *= inv; r[2] *= inv; r[3] *= inv;
            *(f32x4*)(Ob + (size_t)(m0w + cl) * 64 + dt * 16 + quad * 4) = r;
        }
    }
}

extern "C" void kernel_launch(void* const* d_in, const int* in_sizes, int n_in,
                              void* d_out, int out_size, void* d_ws, size_t ws_size,
                              hipStream_t stream) {
    const float* x  = (const float*)d_in[0];
    const float* Wq = (const float*)d_in[1];
    const float* Wk = (const float*)d_in[2];
    const float* Wv = (const float*)d_in[3];
    float* out = (float*)d_out;

    // ws: xb 8MB | wc 6MB | QKV natural 24MB | VT3 8MB = 46MB
    unsigned short* xb  = (unsigned short*)d_ws;
    unsigned short* wc  = xb + (size_t)4096 * 1024;
    unsigned short* qkv = wc + (size_t)3 * 1024 * 1024;
    unsigned short* vt  = qkv + (size_t)3 * 4096 * 1024;

    hipLaunchKernelGGL(cast_all, dim3(7168), dim3(256), 0, stream, x, Wq, Wk, Wv, xb, wc);
    hipLaunchKernelGGL(gemm_qkv, dim3(8, 32, 3), dim3(256), 0, stream, xb, wc, qkv);
    hipLaunchKernelGGL(vtrans, dim3(16, 32), dim3(256), 0, stream, qkv + (size_t)2 * 4096 * 1024, vt);
    hipLaunchKernelGGL(attn, dim3(256), dim3(512), 0, stream, qkv, vt, out);
}

// Round 15
// 148.587 us; speedup vs baseline: 1.0041x; 1.0041x over previous
//
#include <hip/hip_runtime.h>
#include <hip/hip_bf16.h>
#include <stdint.h>

#define AS1 __attribute__((address_space(1)))
#define AS3 __attribute__((address_space(3)))

typedef __bf16 bf16x8 __attribute__((ext_vector_type(8)));
typedef float  f32x4  __attribute__((ext_vector_type(4)));
typedef unsigned short ushort8v __attribute__((ext_vector_type(8)));
typedef unsigned short ushort4v __attribute__((ext_vector_type(4)));
typedef short short8v __attribute__((ext_vector_type(8)));
typedef short short4v __attribute__((ext_vector_type(4)));

__device__ __forceinline__ unsigned short f2bf(float f) {
    unsigned int u = __float_as_uint(f);
    u += 0x7fffu + ((u >> 16) & 1u);           // round-to-nearest-even
    return (unsigned short)(u >> 16);
}
__device__ __forceinline__ unsigned int pk2bf(float a, float b) {
    __hip_bfloat162 h = __float22bfloat162_rn(make_float2(a, b));  // x->low short
    unsigned int u;
    __builtin_memcpy(&u, &h, 4);
    return u;
}
__device__ __forceinline__ void g2lds16(const void* gp, void* lp) {
    __builtin_amdgcn_global_load_lds((AS1 void*)gp, (AS3 void*)lp, 16, 0, 0);
}
#define E2(x) __builtin_amdgcn_exp2f(x)

// ---------------- cast fp32 -> bf16 (x, Wq, Wk, Wv in one launch) -----------
__global__ __launch_bounds__(256) void cast_all(const float* __restrict__ x,
                                                const float* __restrict__ w0,
                                                const float* __restrict__ w1,
                                                const float* __restrict__ w2,
                                                unsigned short* __restrict__ xb,
                                                unsigned short* __restrict__ wc) {
    int id = blockIdx.x;
    const float* s;
    unsigned short* d;
    int base;
    if (id < 4096) { s = x; d = xb; base = id; }
    else {
        int z = (id - 4096) >> 10;
        s = (z == 0) ? w0 : (z == 1) ? w1 : w2;
        d = wc + (size_t)z * 1048576;
        base = (id - 4096) & 1023;
    }
    int i = (base * 256 + threadIdx.x) * 4;
    float4 v = *(const float4*)(s + i);
    ushort4v o = { f2bf(v.x), f2bf(v.y), f2bf(v.z), f2bf(v.w) };
    *(ushort4v*)(d + i) = o;
}

// ---------------- QKV GEMM: X @ W^T (NT), m97 structure (R9-exact) -----------
// Q (z=0) pre-scaled by 0.125*log2(e) so attn can exp2 scores directly.
// Known plateau: 645 TF for this K=1024 shape; dbuf (R10) and BK=64 swizzle
// (R6) both regressed/neutral — at 3 blocks/CU the implicit cross-block
// overlap (m114) already hides staging; do not re-add dbuf.
__global__ __launch_bounds__(256) void gemm_qkv(const unsigned short* __restrict__ X,
                                                const unsigned short* __restrict__ W,
                                                unsigned short* __restrict__ QKV) {
    const int K = 1024, N = 1024;
    const int z = blockIdx.z;
    const unsigned short* A = X;
    const unsigned short* B = W + (size_t)z * (1024 * 1024);
    unsigned short* C = QKV + (size_t)z * (4096 * 1024);
    const float qs = (z == 0) ? 0.18033688011112042f : 1.0f;

    const int m0 = blockIdx.y * 128;
    const int n0 = blockIdx.x * 128;

    __shared__ unsigned short As[128 * 32];
    __shared__ unsigned short Bs[128 * 32];

    const int t = threadIdx.x;
    const int w = t >> 6;
    const int l = t & 63;
    const int wm = (w >> 1) * 64;
    const int wn = (w & 1) * 64;
    const int cl = l & 15;
    const int quad = l >> 4;

    const int srow = w * 16 + (l >> 2);
    const int scol = (l & 3) * 8;

    f32x4 acc[4][4] = {};

    for (int k0 = 0; k0 < K; k0 += 32) {
        g2lds16(A + (size_t)(m0 + srow) * K + k0 + scol,      As + w * 512);
        g2lds16(A + (size_t)(m0 + 64 + srow) * K + k0 + scol, As + 2048 + w * 512);
        g2lds16(B + (size_t)(n0 + srow) * K + k0 + scol,      Bs + w * 512);
        g2lds16(B + (size_t)(n0 + 64 + srow) * K + k0 + scol, Bs + 2048 + w * 512);
        __syncthreads();

        bf16x8 af[4], bfr[4];
        #pragma unroll
        for (int i = 0; i < 4; ++i)
            af[i] = *(const bf16x8*)(As + (wm + i * 16 + cl) * 32 + quad * 8);
        #pragma unroll
        for (int j = 0; j < 4; ++j)
            bfr[j] = *(const bf16x8*)(Bs + (wn + j * 16 + cl) * 32 + quad * 8);
        #pragma unroll
        for (int i = 0; i < 4; ++i)
            #pragma unroll
            for (int j = 0; j < 4; ++j)
                acc[i][j] = __builtin_amdgcn_mfma_f32_16x16x32_bf16(af[i], bfr[j], acc[i][j], 0, 0, 0);
        __syncthreads();
    }

    #pragma unroll
    for (int i = 0; i < 4; ++i) {
        #pragma unroll
        for (int r = 0; r < 4; ++r) {
            size_t row = (size_t)(m0 + wm + i * 16 + quad * 4 + r);
            #pragma unroll
            for (int j = 0; j < 4; ++j)
                C[row * N + (n0 + wn + j * 16 + cl)] = f2bf(acc[i][j][r] * qs);
        }
    }
}

// ---------------- V swizzle to VT3 (per bh) ---------------------------------
// VT3 element (tau, d) at (tau>>4)*1024 + (d&15)*64 + ((tau>>2)&3)*16
//                        + (d>>4)*4 + (tau&3)
// (R11 lesson: direct VT3 write from the GEMM tiling is impossible — tau low
// bits come from the column/head index; this 4µs kernel is the right answer.)
__global__ __launch_bounds__(256) void vtrans(const unsigned short* __restrict__ Vn,
                                              unsigned short* __restrict__ V3) {
    const int bh = blockIdx.y;
    const int T0 = blockIdx.x * 128;
    __shared__ unsigned short L[128 * 72];
    const int t = threadIdx.x;

    const unsigned short* src = Vn + (size_t)bh * 131072 + (size_t)T0 * 64;
    #pragma unroll
    for (int p = 0; p < 4; ++p) {
        int r = p * 32 + (t >> 3), c = (t & 7) * 8;
        *(ushort8v*)(L + r * 72 + c) = *(const ushort8v*)(src + (size_t)r * 64 + c);
    }
    __syncthreads();
    unsigned short* dst = V3 + (size_t)bh * 131072 + (size_t)(T0 >> 4) * 1024;
    #pragma unroll
    for (int p = 0; p < 2; ++p) {
        int item = p * 256 + t;                 // 512 items: kb(8) x cl(16) x qk(4)
        int kb = item >> 6, cl = (item >> 2) & 15, qk = item & 3;
        ushort8v a, b;
        #pragma unroll
        for (int u = 0; u < 8; ++u) {
            int dt = u >> 2, j = u & 3;
            a[u] = L[(kb * 16 + qk * 4 + j) * 72 + dt * 16 + cl];
            b[u] = L[(kb * 16 + qk * 4 + j) * 72 + (dt + 2) * 16 + cl];
        }
        unsigned short* dp = dst + kb * 1024 + cl * 64 + qk * 16;
        *(ushort8v*)(dp) = a;
        *(ushort8v*)(dp + 8) = b;
    }
}

// ---------------- Flash attention: 8-wave block, 128-row band, LDS pipeline --
// Measured-best structure (R13, 147.9us total). 512-thread blocks: 8 waves x
// 16 rows = 128-row band sharing ONE staged K/V stream; single-barrier dbuf
// [barrier; stage(c+1); compute(c)]. Bands paired (pp, 15-pp): 34 staged
// chunks per block, uniform over 256 blocks (1/CU, 2 waves/SIMD). Diagonal:
// wave w masks at chunk 2bb+(w>>2), in-chunk row base (w&3)*16+cl; earlier
// waves skip the final chunk. XCD-pinned (4 bh/XCD). Plateau evidence:
// 2x4-wave blocks (R9), 128-kv chunks (R14) and band-merge (R10) all land
// within 1% — barrier-cadence latency at 2 waves/SIMD is the structural
// floor at source level (cf. m131-m141: finer vmcnt control is compiler-
// defeated; closing the remaining 4x needs hipBLASLt-style hand asm).
__global__ __launch_bounds__(512) void attn(const unsigned short* __restrict__ QK,
                                            const unsigned short* __restrict__ V3,
                                            float* __restrict__ Out) {
    const int id = blockIdx.x;                         // 256 blocks
    const int bh = (id & 7) * 4 + ((id >> 3) & 3);     // 4 bh per XCD
    const int pp = id >> 5;                            // band-pair 0..7
    const int t = threadIdx.x;                         // 0..511
    const int w = t >> 6;                              // wave 0..7
    const int l = t & 63;
    const int cl = l & 15;
    const int quad = l >> 4;
    const int c7 = cl & 7;

    const size_t bhoff = (size_t)bh * 131072;
    const unsigned short* Qb = QK + bhoff;
    const unsigned short* Kb = QK + (size_t)4194304 + bhoff;
    const unsigned short* Vb = V3 + bhoff;
    float* Ob = Out + bhoff;

    __shared__ unsigned short KVs[2][8192];            // per buf: K 4096 | V 4096

    // staging offsets: thread t stages K granule t and V granule t (R9 swizzle)
    const int sg = t;
    const int kO = (sg >> 3) * 64 + (((sg & 7) ^ ((sg >> 3) & 7)) * 8);
    const int wg = sg & 63;
    const int vO = (sg >> 6) * 512 + ((wg ^ ((wg >> 3) & 7)) * 8);
    const int lB = w * 512;                            // shorts (wave-uniform)

    // read offsets (R9-verified)
    const int oK0 = cl * 64 + (((quad)     ^ c7) * 8);
    const int oK1 = cl * 64 + (((quad + 4) ^ c7) * 8);
    const int oV0 = cl * 64 + (((quad * 2)     ^ c7) * 8);
    const int oV1 = cl * 64 + (((quad * 2 + 1) ^ c7) * 8);

    const int mrel = (w & 3) * 16 + cl;                // diag row rel. chunk base

    #pragma unroll 1                                   // R6 lesson: no state merge
    for (int hb = 0; hb < 2; ++hb) {
        const int bb = hb ? (15 - pp) : pp;            // 128-row band index
        const int nchB = 2 * bb + 2;                   // staged 64-kv chunks
        const int myLast = 2 * bb + (w >> 2);          // last chunk this wave computes
        const int m0w = bb * 128 + w * 16;

        bf16x8 qf0, qf1;
        {
            const unsigned short* qa = Qb + (size_t)(m0w + cl) * 64 + quad * 8;
            qf0 = *(const bf16x8*)(qa);
            qf1 = *(const bf16x8*)(qa + 32);
        }

        f32x4 o[4] = {};
        float lps = 0.f;

        // stage chunk 0 into buf 0
        {
            unsigned short* s = &KVs[0][0];
            g2lds16(Kb + kO, s + lB);
            g2lds16(Vb + vO, s + 4096 + lB);
        }

        for (int c = 0; c < nchB; ++c) {
            __syncthreads();                           // buf[c&1] ready
            if (c + 1 < nchB) {
                unsigned short* s = &KVs[(c + 1) & 1][0];
                g2lds16(Kb + (size_t)(c + 1) * 4096 + kO, s + lB);
                g2lds16(Vb + (size_t)(c + 1) * 4096 + vO, s + 4096 + lB);
            }
            if (c > myLast) continue;                  // wave-uniform skip
            const unsigned short* Kl = &KVs[c & 1][0];
            const unsigned short* Vl = Kl + 4096;
            const bool masked = (c == myLast);

            bf16x8 kf0[4], kf1[4];
            #pragma unroll
            for (int kt = 0; kt < 4; ++kt) {
                kf0[kt] = *(const bf16x8*)(Kl + kt * 1024 + oK0);
                kf1[kt] = *(const bf16x8*)(Kl + kt * 1024 + oK1);
            }
            f32x4 st[4] = {};
            #pragma unroll
            for (int kt = 0; kt < 4; ++kt) {
                st[kt] = __builtin_amdgcn_mfma_f32_16x16x32_bf16(kf0[kt], qf0, st[kt], 0, 0, 0);
                st[kt] = __builtin_amdgcn_mfma_f32_16x16x32_bf16(kf1[kt], qf1, st[kt], 0, 0, 0);
            }

            short4v pb[4];
            #pragma unroll
            for (int kt = 0; kt < 4; ++kt) {
                float p0, p1, p2, p3;
                if (masked) {
                    const int lk = kt * 16 + quad * 4;
                    p0 = (lk     <= mrel) ? E2(st[kt][0]) : 0.f;
                    p1 = (lk + 1 <= mrel) ? E2(st[kt][1]) : 0.f;
                    p2 = (lk + 2 <= mrel) ? E2(st[kt][2]) : 0.f;
                    p3 = (lk + 3 <= mrel) ? E2(st[kt][3]) : 0.f;
                } else {
                    p0 = E2(st[kt][0]);
                    p1 = E2(st[kt][1]);
                    p2 = E2(st[kt][2]);
                    p3 = E2(st[kt][3]);
                }
                lps += (p0 + p1) + (p2 + p3);
                uint2 u = { pk2bf(p0, p1), pk2bf(p2, p3) };
                short4v pv;
                __builtin_memcpy(&pv, &u, 8);
                pb[kt] = pv;
            }

            #pragma unroll
            for (int kt = 0; kt < 4; ++kt) {
                short8v v0 = *(const short8v*)(Vl + kt * 1024 + oV0);  // dt 0,1
                short8v v1 = *(const short8v*)(Vl + kt * 1024 + oV1);  // dt 2,3
                short4v a0 = __builtin_shufflevector(v0, v0, 0, 1, 2, 3);
                short4v a1 = __builtin_shufflevector(v0, v0, 4, 5, 6, 7);
                short4v a2 = __builtin_shufflevector(v1, v1, 0, 1, 2, 3);
                short4v a3 = __builtin_shufflevector(v1, v1, 4, 5, 6, 7);
                o[0] = __builtin_amdgcn_mfma_f32_16x16x16bf16_1k(a0, pb[kt], o[0], 0, 0, 0);
                o[1] = __builtin_amdgcn_mfma_f32_16x16x16bf16_1k(a1, pb[kt], o[1], 0, 0, 0);
                o[2] = __builtin_amdgcn_mfma_f32_16x16x16bf16_1k(a2, pb[kt], o[2], 0, 0, 0);
                o[3] = __builtin_amdgcn_mfma_f32_16x16x16bf16_1k(a3, pb[kt], o[3], 0, 0, 0);
            }
        }
        __syncthreads();                               // buf reuse across bands

        lps += __shfl_xor(lps, 16);
        lps += __shfl_xor(lps, 32);
        const float inv = 1.0f / lps;
        #pragma unroll
        for (int dt = 0; dt < 4; ++dt) {
            f32x4 r = o[dt];
            r[0] *= inv; r[1] *= inv; r[2] *= inv; r[3] *= inv;
            *(f32x4*)(Ob + (size_t)(m0w + cl) * 64 + dt * 16 + quad * 4) = r;
        }
    }
}

extern "C" void kernel_launch(void* const* d_in, const int* in_sizes, int n_in,
                              void* d_out, int out_size, void* d_ws, size_t ws_size,
                              hipStream_t stream) {
    const float* x  = (const float*)d_in[0];
    const float* Wq = (const float*)d_in[1];
    const float* Wk = (const float*)d_in[2];
    const float* Wv = (const float*)d_in[3];
    float* out = (float*)d_out;

    // ws: xb 8MB | wc 6MB | QKV natural 24MB | VT3 8MB = 46MB
    unsigned short* xb  = (unsigned short*)d_ws;
    unsigned short* wc  = xb + (size_t)4096 * 1024;
    unsigned short* qkv = wc + (size_t)3 * 1024 * 1024;
    unsigned short* vt  = qkv + (size_t)3 * 4096 * 1024;

    hipLaunchKernelGGL(cast_all, dim3(7168), dim3(256), 0, stream, x, Wq, Wk, Wv, xb, wc);
    hipLaunchKernelGGL(gemm_qkv, dim3(8, 32, 3), dim3(256), 0, stream, xb, wc, qkv);
    hipLaunchKernelGGL(vtrans, dim3(16, 32), dim3(256), 0, stream, qkv + (size_t)2 * 4096 * 1024, vt);
    hipLaunchKernelGGL(attn, dim3(256), dim3(512), 0, stream, qkv, vt, out);
}